// Round 18
// baseline (254.071 us; speedup 1.0000x reference)
//
#include <hip/hip_runtime.h>
#include <cstddef>
#include <cstdint>

// Problem constants (match reference)
constexpr int CB  = 2;     // batch
constexpr int CS  = 2048;  // seq len
constexpr int CDM = 1024;  // d_model
constexpr int CH  = 16;    // heads
constexpr int CHD = 64;    // head dim
constexpr int CTPF = 128;  // tokens per frame
constexpr int CNF = 16;    // frames

typedef __attribute__((ext_vector_type(8))) short short8;
typedef __attribute__((ext_vector_type(4))) float f32x4;

__device__ inline ushort f32_bf16_rne(float x) {
  uint32_t u = __float_as_uint(x);
  u += 0x7FFFu + ((u >> 16) & 1u);
  return (ushort)(u >> 16);
}
__device__ inline float bf16_f32(ushort h) {
  return __uint_as_float(((uint32_t)h) << 16);
}
// split 8 floats into hi/lo bf16 vectors
__device__ inline void split8(const float* v, short8& H, short8& L) {
#pragma unroll
  for (int j = 0; j < 8; ++j) {
    const ushort hh = f32_bf16_rne(v[j]);
    H[j] = (short)hh;
    L[j] = (short)f32_bf16_rne(v[j] - bf16_f32(hh));
  }
}

// ---------------------------------------------------------------------------
// rope_tab: precompute cos/sin for the 65536 distinct (s, j) RoPE angles.
// Bit-identical expressions to what qkv_prep used to compute per-(h,b).
// ---------------------------------------------------------------------------
__global__ __launch_bounds__(256) void rope_tab(float2* __restrict__ T) {
  const int idx = blockIdx.x * 256 + threadIdx.x;  // [0, 65536)
  const int s = idx >> 5;
  const int j = idx & 31;
  const float inv = powf(10000.0f, -(float)j * (1.0f / 32.0f));
  const float ang = (float)s * inv;
  T[idx] = make_float2(cosf(ang), sinf(ang));
}

// ---------------------------------------------------------------------------
// split3: one launch splits x, Wqkv, Wout fp32 -> bf16 h/l. Grid-stride.
// ---------------------------------------------------------------------------
__global__ __launch_bounds__(256) void split3(
    const float* __restrict__ s0, ushort* __restrict__ h0,
    ushort* __restrict__ l0, int n0,
    const float* __restrict__ s1, ushort* __restrict__ h1,
    ushort* __restrict__ l1, int n1,
    const float* __restrict__ s2, ushort* __restrict__ h2,
    ushort* __restrict__ l2, int n2) {
  const int ntot = n0 + n1 + n2;
  int i = blockIdx.x * 256 + threadIdx.x;
  const int stride = gridDim.x * 256;
  for (; i < ntot; i += stride) {
    const float* src;
    ushort *h, *l;
    int j = i;
    if (j < n0) {
      src = s0; h = h0; l = l0;
    } else if ((j -= n0) < n1) {
      src = s1; h = h1; l = l1;
    } else {
      j -= n1; src = s2; h = h2; l = l2;
    }
    float v[8];
    *(float4*)&v[0] = ((const float4*)src)[2 * j];
    *(float4*)&v[4] = ((const float4*)src)[2 * j + 1];
    short8 H, L;
    split8(v, H, L);
    *(short8*)&h[(size_t)j * 8] = H;
    *(short8*)&l[(size_t)j * 8] = L;
  }
}

// ---------------------------------------------------------------------------
// gemm_ps v2 (validated R13/R16): C[M,N] = A[M,K] @ B[N,K]^T + bias[N],
// pre-split bf16 h/l. global_load_lds width=16, pre-swizzled global source,
// linear LDS dest, conflict-free reads. 32 KB LDS.
// ---------------------------------------------------------------------------
__global__ __launch_bounds__(256) void gemm_ps(
    const ushort* __restrict__ Ah, const ushort* __restrict__ Al,
    const ushort* __restrict__ Bh, const ushort* __restrict__ Bl,
    const float* __restrict__ bias, float* __restrict__ C,
    int M, int N, int K) {
  __shared__ ushort As_h[128 * 32], As_l[128 * 32];
  __shared__ ushort Bs_h[128 * 32], Bs_l[128 * 32];
  const int tid = threadIdx.x;
  const int bm = blockIdx.y * 128;
  const int bn = blockIdx.x * 128;
  const int wid = tid >> 6;
  const int lane = tid & 63;
  const int wm = wid >> 1;
  const int wn = wid & 1;
  const int l15 = lane & 15;
  const int lk = lane >> 4;
  const int srow = tid >> 2;
  const int kq = (tid & 3) * 8;

  f32x4 acc[4][4];
#pragma unroll
  for (int i = 0; i < 4; ++i)
#pragma unroll
    for (int j = 0; j < 4; ++j) acc[i][j] = (f32x4){0.f, 0.f, 0.f, 0.f};

  for (int k0 = 0; k0 < K; k0 += 32) {
    __syncthreads();
#pragma unroll
    for (int c = 0; c < 2; ++c) {
      const int row = srow + c * 64;
      const int kg = kq ^ ((row & 6) << 2);
      const size_t ga = (size_t)(bm + row) * K + k0 + kg;
      const size_t gb = (size_t)(bn + row) * K + k0 + kg;
      const int lo = tid * 8 + c * 2048;
      __builtin_amdgcn_global_load_lds(
          (const __attribute__((address_space(1))) void*)(Ah + ga),
          (__attribute__((address_space(3))) void*)&As_h[lo], 16, 0, 0);
      __builtin_amdgcn_global_load_lds(
          (const __attribute__((address_space(1))) void*)(Al + ga),
          (__attribute__((address_space(3))) void*)&As_l[lo], 16, 0, 0);
      __builtin_amdgcn_global_load_lds(
          (const __attribute__((address_space(1))) void*)(Bh + gb),
          (__attribute__((address_space(3))) void*)&Bs_h[lo], 16, 0, 0);
      __builtin_amdgcn_global_load_lds(
          (const __attribute__((address_space(1))) void*)(Bl + gb),
          (__attribute__((address_space(3))) void*)&Bs_l[lo], 16, 0, 0);
    }
    __syncthreads();

    short8 ah[4], al[4], bh[4], bl[4];
#pragma unroll
    for (int fI = 0; fI < 4; ++fI) {
      const int ar = wm * 64 + fI * 16 + l15;
      const int aoff = ar * 32 + ((lk * 8) ^ ((ar & 6) << 2));
      ah[fI] = *(const short8*)&As_h[aoff];
      al[fI] = *(const short8*)&As_l[aoff];
      const int br = wn * 64 + fI * 16 + l15;
      const int boff = br * 32 + ((lk * 8) ^ ((br & 6) << 2));
      bh[fI] = *(const short8*)&Bs_h[boff];
      bl[fI] = *(const short8*)&Bs_l[boff];
    }
#pragma unroll
    for (int mf = 0; mf < 4; ++mf)
#pragma unroll
      for (int nf = 0; nf < 4; ++nf) {
        acc[mf][nf] = __builtin_amdgcn_mfma_f32_16x16x32_bf16(
            ah[mf], bh[nf], acc[mf][nf], 0, 0, 0);
        acc[mf][nf] = __builtin_amdgcn_mfma_f32_16x16x32_bf16(
            ah[mf], bl[nf], acc[mf][nf], 0, 0, 0);
        acc[mf][nf] = __builtin_amdgcn_mfma_f32_16x16x32_bf16(
            al[mf], bh[nf], acc[mf][nf], 0, 0, 0);
      }
  }

#pragma unroll
  for (int mf = 0; mf < 4; ++mf)
#pragma unroll
    for (int nf = 0; nf < 4; ++nf) {
      const int col = bn + wn * 64 + nf * 16 + l15;
      const int row0 = bm + wm * 64 + mf * 16 + lk * 4;
      const float bc = bias[col];
#pragma unroll
      for (int i = 0; i < 4; ++i)
        C[(size_t)(row0 + i) * N + col] = acc[mf][nf][i] + bc;
    }
}

// ---------------------------------------------------------------------------
// qkv_prep v4: RMSNorm + RoPE (table) + pre-split to bf16 h/l.
//   Qh/Ql [B,H,S,64] linear (attn reads Q to regs directly)
//   Kh/Kl [B,H,S,64] with col d ^ ((s&7)<<3)  (pre-swizzled for gload_lds)
//   Vth/Vtl [B,H,64,S] with in-chunk col s64 ^ ((d&7)<<3)
// Swizzles are within-128B-line permutations -> prep coalescing unchanged;
// attn stages these linearly via global_load_lds and applies the same XOR
// on LDS reads (rule: inverse-swz source + linear dest + swz read).
// Trig comes from the rope_tab table (bit-identical values).
// ---------------------------------------------------------------------------
__global__ __launch_bounds__(256) void qkv_prep(
    const float* __restrict__ qkv, const float* __restrict__ q_scale,
    const float* __restrict__ k_scale, const float2* __restrict__ Trig,
    ushort* __restrict__ Qh, ushort* __restrict__ Ql,
    ushort* __restrict__ Kh, ushort* __restrict__ Kl,
    ushort* __restrict__ Vth, ushort* __restrict__ Vtl) {
  __shared__ float Vtile[64][68];
  const int lane = threadIdx.x & 63;
  const int w = threadIdx.x >> 6;
  const int st = blockIdx.x;   // s-tile of 64
  const int h = blockIdx.y;
  const int b = blockIdx.z;

  const float qs = q_scale[lane];
  const float ks = k_scale[lane];
  const int j = lane & 31;
  const float sgn = (lane < 32) ? -1.f : 1.f;

  for (int it = 0; it < 16; ++it) {
    const int sl = w * 16 + it;
    const int s = st * 64 + sl;
    const size_t row =
        ((size_t)(b * CS + s)) * (3 * CDM) + (size_t)h * CHD + lane;
    float qv = qkv[row];
    float kv = qkv[row + CDM];
    const float vv = qkv[row + 2 * CDM];

    float sq = qv * qv, sk2 = kv * kv;
#pragma unroll
    for (int off = 32; off > 0; off >>= 1) {
      sq += __shfl_xor(sq, off);
      sk2 += __shfl_xor(sk2, off);
    }
    qv *= rsqrtf(sq * (1.f / CHD) + 1e-6f) * qs;
    kv *= rsqrtf(sk2 * (1.f / CHD) + 1e-6f) * ks;

    const float2 cstab = Trig[s * 32 + j];
    const float cs = cstab.x;
    const float sn = cstab.y;
    const float qp = __shfl_xor(qv, 32);
    const float kp = __shfl_xor(kv, 32);
    const float qr = fmaf(qv, cs, sgn * qp * sn) * 0.125f;  // pre-scale Q
    const float kr = fmaf(kv, cs, sgn * kp * sn);

    const size_t tok = ((size_t)(b * CH + h)) * CS + s;
    const size_t obq = tok * CHD + lane;
    const ushort qhh = f32_bf16_rne(qr);
    Qh[obq] = qhh;
    Ql[obq] = f32_bf16_rne(qr - bf16_f32(qhh));
    // K pre-swizzled: col = d ^ ((s&7)<<3)  (within-128B permutation)
    const size_t obk = tok * CHD + (lane ^ ((s & 7) << 3));
    const ushort khh = f32_bf16_rne(kr);
    Kh[obk] = khh;
    Kl[obk] = f32_bf16_rne(kr - bf16_f32(khh));
    Vtile[lane][sl] = vv;
  }
  __syncthreads();
  // write Vt[b,h,d, st*64 ..] split h/l, pre-swizzled in-chunk col
  const int d = threadIdx.x >> 2;
  const int sq4 = (threadIdx.x & 3) * 16;
  const size_t vrow = (((size_t)(b * CH + h)) * CHD + d) * CS + st * 64;
  const int vmk = (d & 7) << 3;
#pragma unroll
  for (int j0 = 0; j0 < 16; j0 += 8) {
    float v8[8];
#pragma unroll
    for (int jj = 0; jj < 8; ++jj) v8[jj] = Vtile[d][sq4 + j0 + jj];
    short8 H, L;
    split8(v8, H, L);
    const int c0 = (sq4 + j0) ^ vmk;  // 8-aligned run stays 8-aligned
    *(short8*)&Vth[vrow + c0] = H;
    *(short8*)&Vtl[vrow + c0] = L;
  }
}

// ---------------------------------------------------------------------------
// attn_fwd_mfma v5: identical math to R16; staging rebuilt on
// global_load_lds (async, no VGPR round-trip, no ds_write):
// K/V arrive pre-swizzled in global memory, LDS dest is LINEAR
// (u = tid*8 + q*2048 -> lane*16B contiguous), reads apply the same XOR
// as before (unchanged formulas).
// ---------------------------------------------------------------------------
__global__ __launch_bounds__(256, 2) void attn_fwd_mfma(
    const ushort* __restrict__ Qh, const ushort* __restrict__ Ql,
    const ushort* __restrict__ Kh, const ushort* __restrict__ Kl,
    const ushort* __restrict__ Vth, const ushort* __restrict__ Vtl,
    ushort* __restrict__ Oh, ushort* __restrict__ Ol) {
  __shared__ ushort Ks_h[64 * 64], Ks_l[64 * 64];   // K chunk [key][d]
  __shared__ ushort Vs_h[64 * 64], Vs_l[64 * 64];   // V^T chunk [d][key]
  __shared__ ushort Ps_h[128 * 64], Ps_l[128 * 64]; // P [q][key], wave-priv
  const int tid = threadIdx.x;
  const int b = blockIdx.x;
  const int h = blockIdx.y;
  const int fsel = blockIdx.z;
  const int f = (fsel < 8) ? (15 - fsel) : (fsel - 8);  // balanced pairing
  const int lane = tid & 63;
  const int wid = tid >> 6;
  const int l15 = lane & 15;
  const int lk = lane >> 4;
  const int qb = wid * 32;
  const size_t hb = ((size_t)(b * CH + h)) * CS * CHD;
  const size_t vtb = ((size_t)(b * CH + h)) * CHD * CS;

  short8 qh[2][2], ql[2][2];
#pragma unroll
  for (int nf = 0; nf < 2; ++nf)
#pragma unroll
    for (int ks = 0; ks < 2; ++ks) {
      const size_t qoff = hb +
          (size_t)(f * CTPF + qb + nf * 16 + l15) * CHD + ks * 32 + lk * 8;
      qh[nf][ks] = *(const short8*)(Qh + qoff);
      ql[nf][ks] = *(const short8*)(Ql + qoff);
    }

  f32x4 accO[2][4];
#pragma unroll
  for (int mo = 0; mo < 2; ++mo)
#pragma unroll
    for (int no = 0; no < 4; ++no) accO[mo][no] = (f32x4){0.f, 0.f, 0.f, 0.f};
  float m[2] = {-1e30f, -1e30f};
  float lsum[2] = {0.f, 0.f};

  const int kf0 = (f == CNF - 1) ? 1 : 0;  // last-frame quirk
  for (int kf = kf0; kf <= f; ++kf) {
#pragma unroll 1
    for (int half = 0; half < 2; ++half) {
      const int cb = kf * CTPF + half * 64;
      __syncthreads();  // prev chunk's readers done before DMA lands
      {
        const size_t kc = hb + (size_t)cb * CHD;  // K chunk: contiguous 4096
#pragma unroll
        for (int q = 0; q < 2; ++q) {
          const int u = tid * 8 + q * 2048;
          __builtin_amdgcn_global_load_lds(
              (const __attribute__((address_space(1))) void*)(Kh + kc + u),
              (__attribute__((address_space(3))) void*)&Ks_h[u], 16, 0, 0);
          __builtin_amdgcn_global_load_lds(
              (const __attribute__((address_space(1))) void*)(Kl + kc + u),
              (__attribute__((address_space(3))) void*)&Ks_l[u], 16, 0, 0);
          const size_t va = vtb + (size_t)(u >> 6) * CS + cb + (u & 63);
          __builtin_amdgcn_global_load_lds(
              (const __attribute__((address_space(1))) void*)(Vth + va),
              (__attribute__((address_space(3))) void*)&Vs_h[u], 16, 0, 0);
          __builtin_amdgcn_global_load_lds(
              (const __attribute__((address_space(1))) void*)(Vtl + va),
              (__attribute__((address_space(3))) void*)&Vs_l[u], 16, 0, 0);
        }
      }
      __syncthreads();  // drains vmcnt: staged data visible

      f32x4 sacc[4][2];
#pragma unroll
      for (int mf = 0; mf < 4; ++mf)
#pragma unroll
        for (int nf = 0; nf < 2; ++nf) sacc[mf][nf] = (f32x4){0.f, 0.f, 0.f, 0.f};
#pragma unroll
      for (int ks = 0; ks < 2; ++ks) {
        short8 kh[4], kl[4];
#pragma unroll
        for (int mf = 0; mf < 4; ++mf) {
          const int krow = mf * 16 + l15;
          const int base = krow * 64 + ((ks * 32 + lk * 8) ^ ((krow & 7) << 3));
          kh[mf] = *(const short8*)&Ks_h[base];
          kl[mf] = *(const short8*)&Ks_l[base];
        }
#pragma unroll
        for (int mf = 0; mf < 4; ++mf)
#pragma unroll
          for (int nf = 0; nf < 2; ++nf) {
            sacc[mf][nf] = __builtin_amdgcn_mfma_f32_16x16x32_bf16(
                kh[mf], qh[nf][ks], sacc[mf][nf], 0, 0, 0);
            sacc[mf][nf] = __builtin_amdgcn_mfma_f32_16x16x32_bf16(
                kh[mf], ql[nf][ks], sacc[mf][nf], 0, 0, 0);
            sacc[mf][nf] = __builtin_amdgcn_mfma_f32_16x16x32_bf16(
                kl[mf], qh[nf][ks], sacc[mf][nf], 0, 0, 0);
          }
      }

      float c[2];
#pragma unroll
      for (int nf = 0; nf < 2; ++nf) {
        float cm = sacc[0][nf][0];
#pragma unroll
        for (int mf = 0; mf < 4; ++mf)
#pragma unroll
          for (int i = 0; i < 4; ++i) cm = fmaxf(cm, sacc[mf][nf][i]);
        cm = fmaxf(cm, __shfl_xor(cm, 16));
        cm = fmaxf(cm, __shfl_xor(cm, 32));
        const float mn = fmaxf(m[nf], cm);
        c[nf] = __expf(m[nf] - mn);
        m[nf] = mn;
        float ps = 0.f;
        const int qrow = qb + nf * 16 + l15;
        const int qmk = (qrow & 7) << 3;
#pragma unroll
        for (int mf = 0; mf < 4; ++mf) {
          float p0 = __expf(sacc[mf][nf][0] - mn);
          float p1 = __expf(sacc[mf][nf][1] - mn);
          float p2 = __expf(sacc[mf][nf][2] - mn);
          float p3 = __expf(sacc[mf][nf][3] - mn);
          ps += (p0 + p1) + (p2 + p3);
          const ushort h0 = f32_bf16_rne(p0), h1 = f32_bf16_rne(p1);
          const ushort h2 = f32_bf16_rne(p2), h3 = f32_bf16_rne(p3);
          uint2 hw, lw;
          hw.x = (uint32_t)h0 | ((uint32_t)h1 << 16);
          hw.y = (uint32_t)h2 | ((uint32_t)h3 << 16);
          lw.x = (uint32_t)f32_bf16_rne(p0 - bf16_f32(h0)) |
                 ((uint32_t)f32_bf16_rne(p1 - bf16_f32(h1)) << 16);
          lw.y = (uint32_t)f32_bf16_rne(p2 - bf16_f32(h2)) |
                 ((uint32_t)f32_bf16_rne(p3 - bf16_f32(h3)) << 16);
          const int off = qrow * 64 + ((mf * 16 + lk * 4) ^ qmk);
          *(uint2*)&Ps_h[off] = hw;
          *(uint2*)&Ps_l[off] = lw;
        }
        ps += __shfl_xor(ps, 16);
        ps += __shfl_xor(ps, 32);
        lsum[nf] = lsum[nf] * c[nf] + ps;
      }
#pragma unroll
      for (int mo = 0; mo < 2; ++mo)
#pragma unroll
        for (int i = 0; i < 4; ++i) {
          const float cq = __shfl(c[mo], lk * 4 + i);
#pragma unroll
          for (int no = 0; no < 4; ++no) accO[mo][no][i] *= cq;
        }

#pragma unroll
      for (int ks = 0; ks < 2; ++ks) {
        short8 pa_h[2], pa_l[2], vb_h[4], vb_l[4];
#pragma unroll
        for (int mo = 0; mo < 2; ++mo) {
          const int qrow = qb + mo * 16 + l15;
          const int base = qrow * 64 + ((ks * 32 + lk * 8) ^ ((qrow & 7) << 3));
          pa_h[mo] = *(const short8*)&Ps_h[base];
          pa_l[mo] = *(const short8*)&Ps_l[base];
        }
#pragma unroll
        for (int no = 0; no < 4; ++no) {
          const int vrow = no * 16 + l15;
          const int base = vrow * 64 + ((ks * 32 + lk * 8) ^ ((vrow & 7) << 3));
          vb_h[no] = *(const short8*)&Vs_h[base];
          vb_l[no] = *(const short8*)&Vs_l[base];
        }
#pragma unroll
        for (int mo = 0; mo < 2; ++mo)
#pragma unroll
          for (int no = 0; no < 4; ++no) {
            accO[mo][no] = __builtin_amdgcn_mfma_f32_16x16x32_bf16(
                pa_h[mo], vb_h[no], accO[mo][no], 0, 0, 0);
            accO[mo][no] = __builtin_amdgcn_mfma_f32_16x16x32_bf16(
                pa_h[mo], vb_l[no], accO[mo][no], 0, 0, 0);
            accO[mo][no] = __builtin_amdgcn_mfma_f32_16x16x32_bf16(
                pa_l[mo], vb_h[no], accO[mo][no], 0, 0, 0);
          }
      }
    }
  }

  const float il0 = 1.f / lsum[0];
  const float il1 = 1.f / lsum[1];
#pragma unroll
  for (int mo = 0; mo < 2; ++mo) {
    const float myil = (mo == 0) ? il0 : il1;
#pragma unroll
    for (int i = 0; i < 4; ++i) {
      const float wv = __shfl(myil, lk * 4 + i);
      const int srow = f * CTPF + qb + mo * 16 + lk * 4 + i;
      const size_t obase = (size_t)(b * CS + srow) * CDM + h * CHD;
#pragma unroll
      for (int no = 0; no < 4; ++no) {
        const float val = accO[mo][no][i] * wv;
        const ushort hh = f32_bf16_rne(val);
        Oh[obase + no * 16 + l15] = hh;
        Ol[obase + no * 16 + l15] = f32_bf16_rne(val - bf16_f32(hh));
      }
    }
  }
}

// ---------------------------------------------------------------------------
extern "C" void kernel_launch(void* const* d_in, const int* in_sizes, int n_in,
                              void* d_out, int out_size, void* d_ws, size_t ws_size,
                              hipStream_t stream) {
  const float* x       = (const float*)d_in[0];
  const float* Wqkv    = (const float*)d_in[1];
  const float* bqkv    = (const float*)d_in[2];
  const float* q_scale = (const float*)d_in[3];
  const float* k_scale = (const float*)d_in[4];
  const float* Wout    = (const float*)d_in[5];
  const float* bout    = (const float*)d_in[6];
  float* out = (float*)d_out;

  // Workspace layout (ushort units). Temporal aliasing (validated R11-R16):
  //  region0 (50.3 MB): qkv fp32 [GEMM1..prep]  ->  Oh/Ol [attn..GEMM2]
  //  region1 (50.3 MB): xh/xl/Wqh/Wql [split..GEMM1] -> Qh..Vtl [prep..attn]
  //  region2 ( 4.2 MB): Wouth/Woutl [split..GEMM2]; then 512KB trig table
  ushort* W = (ushort*)d_ws;
  const size_t qkvN = (size_t)(CB * CS) * (3 * CDM);   // 12.58M floats
  const size_t perA = (size_t)CB * CH * CS * CHD;      // 4.19M elems
  const size_t WqN  = (size_t)(3 * CDM) * CDM;         // 3.15M
  const size_t WoN  = (size_t)CDM * CDM;               // 1.05M

  float*  qkvF = (float*)W;
  ushort* Oh   = W;                    // aliases qkvF (dead after prep)
  ushort* Ol   = W + perA;
  ushort* R1   = W + 2 * qkvN;
  ushort* Qh = R1;            ushort* Ql = R1 + perA;
  ushort* Kh = R1 + 2 * perA; ushort* Kl = R1 + 3 * perA;
  ushort* Vth = R1 + 4 * perA; ushort* Vtl = R1 + 5 * perA;
  ushort* xh  = R1;            ushort* xl  = R1 + perA;   // alias Qh/Ql
  ushort* Wqh = R1 + 2 * perA; ushort* Wql = Wqh + WqN;   // alias Kh..
  ushort* Wouth = R1 + 6 * perA; ushort* Woutl = Wouth + WoN;
  float2* Trig = (float2*)(Woutl + WoN);               // 65536 float2

  // 0) one-time splits + RoPE trig table
  rope_tab<<<256, 256, 0, stream>>>(Trig);
  split3<<<2048, 256, 0, stream>>>(x, xh, xl, (int)(perA / 8),
                                   Wqkv, Wqh, Wql, (int)(WqN / 8),
                                   Wout, Wouth, Woutl, (int)(WoN / 8));

  // 1) qkv = x @ Wqkv^T + bqkv
  dim3 g1((3 * CDM) / 128, (CB * CS) / 128);
  gemm_ps<<<g1, 256, 0, stream>>>(xh, xl, Wqh, Wql, bqkv, qkvF,
                                  CB * CS, 3 * CDM, CDM);

  // 2) RMSNorm + RoPE (table); pre-split Q linear, K/V pre-swizzled
  dim3 g2(CS / 64, CH, CB);
  qkv_prep<<<g2, 256, 0, stream>>>(qkvF, q_scale, k_scale, Trig,
                                   Qh, Ql, Kh, Kl, Vth, Vtl);

  // 3) frame-block-causal attention on MFMA -> pre-split O
  dim3 g3(CB, CH, CNF);
  attn_fwd_mfma<<<g3, 256, 0, stream>>>(Qh, Ql, Kh, Kl, Vth, Vtl, Oh, Ol);

  // 4) out = O @ Wout^T + bout
  dim3 g4(CDM / 128, (CB * CS) / 128);
  gemm_ps<<<g4, 256, 0, stream>>>(Oh, Ol, Wouth, Woutl, bout, out,
                                  CB * CS, CDM, CDM);
}

// Round 19
// 246.369 us; speedup vs baseline: 1.0313x; 1.0313x over previous
//
#include <hip/hip_runtime.h>
#include <cstddef>
#include <cstdint>

// Problem constants (match reference)
constexpr int CB  = 2;     // batch
constexpr int CS  = 2048;  // seq len
constexpr int CDM = 1024;  // d_model
constexpr int CH  = 16;    // heads
constexpr int CHD = 64;    // head dim
constexpr int CTPF = 128;  // tokens per frame
constexpr int CNF = 16;    // frames

typedef __attribute__((ext_vector_type(8))) short short8;
typedef __attribute__((ext_vector_type(4))) float f32x4;

__device__ inline ushort f32_bf16_rne(float x) {
  uint32_t u = __float_as_uint(x);
  u += 0x7FFFu + ((u >> 16) & 1u);
  return (ushort)(u >> 16);
}
__device__ inline float bf16_f32(ushort h) {
  return __uint_as_float(((uint32_t)h) << 16);
}
// split 8 floats into hi/lo bf16 vectors
__device__ inline void split8(const float* v, short8& H, short8& L) {
#pragma unroll
  for (int j = 0; j < 8; ++j) {
    const ushort hh = f32_bf16_rne(v[j]);
    H[j] = (short)hh;
    L[j] = (short)f32_bf16_rne(v[j] - bf16_f32(hh));
  }
}

// ---------------------------------------------------------------------------
// rope_tab: precompute cos/sin for the 65536 distinct (s, j) RoPE angles.
// ---------------------------------------------------------------------------
__global__ __launch_bounds__(256) void rope_tab(float2* __restrict__ T) {
  const int idx = blockIdx.x * 256 + threadIdx.x;  // [0, 65536)
  const int s = idx >> 5;
  const int j = idx & 31;
  const float inv = powf(10000.0f, -(float)j * (1.0f / 32.0f));
  const float ang = (float)s * inv;
  T[idx] = make_float2(cosf(ang), sinf(ang));
}

// ---------------------------------------------------------------------------
// split3: one launch splits x, Wqkv, Wout fp32 -> bf16 h/l. Grid-stride.
// ---------------------------------------------------------------------------
__global__ __launch_bounds__(256) void split3(
    const float* __restrict__ s0, ushort* __restrict__ h0,
    ushort* __restrict__ l0, int n0,
    const float* __restrict__ s1, ushort* __restrict__ h1,
    ushort* __restrict__ l1, int n1,
    const float* __restrict__ s2, ushort* __restrict__ h2,
    ushort* __restrict__ l2, int n2) {
  const int ntot = n0 + n1 + n2;
  int i = blockIdx.x * 256 + threadIdx.x;
  const int stride = gridDim.x * 256;
  for (; i < ntot; i += stride) {
    const float* src;
    ushort *h, *l;
    int j = i;
    if (j < n0) {
      src = s0; h = h0; l = l0;
    } else if ((j -= n0) < n1) {
      src = s1; h = h1; l = l1;
    } else {
      j -= n1; src = s2; h = h2; l = l2;
    }
    float v[8];
    *(float4*)&v[0] = ((const float4*)src)[2 * j];
    *(float4*)&v[4] = ((const float4*)src)[2 * j + 1];
    short8 H, L;
    split8(v, H, L);
    *(short8*)&h[(size_t)j * 8] = H;
    *(short8*)&l[(size_t)j * 8] = L;
  }
}

// ---------------------------------------------------------------------------
// gemm_ps v2 (validated R13/R16): C[M,N] = A[M,K] @ B[N,K]^T + bias[N],
// pre-split bf16 h/l. global_load_lds width=16, pre-swizzled global source,
// linear LDS dest, conflict-free reads. 32 KB LDS.
// ---------------------------------------------------------------------------
__global__ __launch_bounds__(256) void gemm_ps(
    const ushort* __restrict__ Ah, const ushort* __restrict__ Al,
    const ushort* __restrict__ Bh, const ushort* __restrict__ Bl,
    const float* __restrict__ bias, float* __restrict__ C,
    int M, int N, int K) {
  __shared__ ushort As_h[128 * 32], As_l[128 * 32];
  __shared__ ushort Bs_h[128 * 32], Bs_l[128 * 32];
  const int tid = threadIdx.x;
  const int bm = blockIdx.y * 128;
  const int bn = blockIdx.x * 128;
  const int wid = tid >> 6;
  const int lane = tid & 63;
  const int wm = wid >> 1;
  const int wn = wid & 1;
  const int l15 = lane & 15;
  const int lk = lane >> 4;
  const int srow = tid >> 2;
  const int kq = (tid & 3) * 8;

  f32x4 acc[4][4];
#pragma unroll
  for (int i = 0; i < 4; ++i)
#pragma unroll
    for (int j = 0; j < 4; ++j) acc[i][j] = (f32x4){0.f, 0.f, 0.f, 0.f};

  for (int k0 = 0; k0 < K; k0 += 32) {
    __syncthreads();
#pragma unroll
    for (int c = 0; c < 2; ++c) {
      const int row = srow + c * 64;
      const int kg = kq ^ ((row & 6) << 2);
      const size_t ga = (size_t)(bm + row) * K + k0 + kg;
      const size_t gb = (size_t)(bn + row) * K + k0 + kg;
      const int lo = tid * 8 + c * 2048;
      __builtin_amdgcn_global_load_lds(
          (const __attribute__((address_space(1))) void*)(Ah + ga),
          (__attribute__((address_space(3))) void*)&As_h[lo], 16, 0, 0);
      __builtin_amdgcn_global_load_lds(
          (const __attribute__((address_space(1))) void*)(Al + ga),
          (__attribute__((address_space(3))) void*)&As_l[lo], 16, 0, 0);
      __builtin_amdgcn_global_load_lds(
          (const __attribute__((address_space(1))) void*)(Bh + gb),
          (__attribute__((address_space(3))) void*)&Bs_h[lo], 16, 0, 0);
      __builtin_amdgcn_global_load_lds(
          (const __attribute__((address_space(1))) void*)(Bl + gb),
          (__attribute__((address_space(3))) void*)&Bs_l[lo], 16, 0, 0);
    }
    __syncthreads();

    short8 ah[4], al[4], bh[4], bl[4];
#pragma unroll
    for (int fI = 0; fI < 4; ++fI) {
      const int ar = wm * 64 + fI * 16 + l15;
      const int aoff = ar * 32 + ((lk * 8) ^ ((ar & 6) << 2));
      ah[fI] = *(const short8*)&As_h[aoff];
      al[fI] = *(const short8*)&As_l[aoff];
      const int br = wn * 64 + fI * 16 + l15;
      const int boff = br * 32 + ((lk * 8) ^ ((br & 6) << 2));
      bh[fI] = *(const short8*)&Bs_h[boff];
      bl[fI] = *(const short8*)&Bs_l[boff];
    }
#pragma unroll
    for (int mf = 0; mf < 4; ++mf)
#pragma unroll
      for (int nf = 0; nf < 4; ++nf) {
        acc[mf][nf] = __builtin_amdgcn_mfma_f32_16x16x32_bf16(
            ah[mf], bh[nf], acc[mf][nf], 0, 0, 0);
        acc[mf][nf] = __builtin_amdgcn_mfma_f32_16x16x32_bf16(
            ah[mf], bl[nf], acc[mf][nf], 0, 0, 0);
        acc[mf][nf] = __builtin_amdgcn_mfma_f32_16x16x32_bf16(
            al[mf], bh[nf], acc[mf][nf], 0, 0, 0);
      }
  }

#pragma unroll
  for (int mf = 0; mf < 4; ++mf)
#pragma unroll
    for (int nf = 0; nf < 4; ++nf) {
      const int col = bn + wn * 64 + nf * 16 + l15;
      const int row0 = bm + wm * 64 + mf * 16 + lk * 4;
      const float bc = bias[col];
#pragma unroll
      for (int i = 0; i < 4; ++i)
        C[(size_t)(row0 + i) * N + col] = acc[mf][nf][i] + bc;
    }
}

// ---------------------------------------------------------------------------
// qkv_prep v4 (validated R18): RMSNorm + RoPE (table) + pre-split bf16 h/l.
//   Qh/Ql linear; Kh/Kl col d ^ ((s&7)<<3); Vth/Vtl col ^ ((d&7)<<3).
// ---------------------------------------------------------------------------
__global__ __launch_bounds__(256) void qkv_prep(
    const float* __restrict__ qkv, const float* __restrict__ q_scale,
    const float* __restrict__ k_scale, const float2* __restrict__ Trig,
    ushort* __restrict__ Qh, ushort* __restrict__ Ql,
    ushort* __restrict__ Kh, ushort* __restrict__ Kl,
    ushort* __restrict__ Vth, ushort* __restrict__ Vtl) {
  __shared__ float Vtile[64][68];
  const int lane = threadIdx.x & 63;
  const int w = threadIdx.x >> 6;
  const int st = blockIdx.x;   // s-tile of 64
  const int h = blockIdx.y;
  const int b = blockIdx.z;

  const float qs = q_scale[lane];
  const float ks = k_scale[lane];
  const int j = lane & 31;
  const float sgn = (lane < 32) ? -1.f : 1.f;

  for (int it = 0; it < 16; ++it) {
    const int sl = w * 16 + it;
    const int s = st * 64 + sl;
    const size_t row =
        ((size_t)(b * CS + s)) * (3 * CDM) + (size_t)h * CHD + lane;
    float qv = qkv[row];
    float kv = qkv[row + CDM];
    const float vv = qkv[row + 2 * CDM];

    float sq = qv * qv, sk2 = kv * kv;
#pragma unroll
    for (int off = 32; off > 0; off >>= 1) {
      sq += __shfl_xor(sq, off);
      sk2 += __shfl_xor(sk2, off);
    }
    qv *= rsqrtf(sq * (1.f / CHD) + 1e-6f) * qs;
    kv *= rsqrtf(sk2 * (1.f / CHD) + 1e-6f) * ks;

    const float2 cstab = Trig[s * 32 + j];
    const float cs = cstab.x;
    const float sn = cstab.y;
    const float qp = __shfl_xor(qv, 32);
    const float kp = __shfl_xor(kv, 32);
    const float qr = fmaf(qv, cs, sgn * qp * sn) * 0.125f;  // pre-scale Q
    const float kr = fmaf(kv, cs, sgn * kp * sn);

    const size_t tok = ((size_t)(b * CH + h)) * CS + s;
    const size_t obq = tok * CHD + lane;
    const ushort qhh = f32_bf16_rne(qr);
    Qh[obq] = qhh;
    Ql[obq] = f32_bf16_rne(qr - bf16_f32(qhh));
    // K pre-swizzled: col = d ^ ((s&7)<<3)  (within-128B permutation)
    const size_t obk = tok * CHD + (lane ^ ((s & 7) << 3));
    const ushort khh = f32_bf16_rne(kr);
    Kh[obk] = khh;
    Kl[obk] = f32_bf16_rne(kr - bf16_f32(khh));
    Vtile[lane][sl] = vv;
  }
  __syncthreads();
  // write Vt[b,h,d, st*64 ..] split h/l, pre-swizzled in-chunk col
  const int d = threadIdx.x >> 2;
  const int sq4 = (threadIdx.x & 3) * 16;
  const size_t vrow = (((size_t)(b * CH + h)) * CHD + d) * CS + st * 64;
  const int vmk = (d & 7) << 3;
#pragma unroll
  for (int j0 = 0; j0 < 16; j0 += 8) {
    float v8[8];
#pragma unroll
    for (int jj = 0; jj < 8; ++jj) v8[jj] = Vtile[d][sq4 + j0 + jj];
    short8 H, L;
    split8(v8, H, L);
    const int c0 = (sq4 + j0) ^ vmk;  // 8-aligned run stays 8-aligned
    *(short8*)&Vth[vrow + c0] = H;
    *(short8*)&Vtl[vrow + c0] = L;
  }
}

// ---------------------------------------------------------------------------
// attn_fwd_mfma v6: wave-reshape for latency hiding. R18 diagnosis: 5170
// cyc/half-chunk vs ~700 cyc visible work -> latency-chain-bound at 2
// waves/SIMD. v6: 512 threads = 8 waves x 16 queries (nf dim dropped):
// per-wave serial chain halves, per-CU waves double (2 blk x 8 = 16/CU =
// 4/SIMD). Same math, same rne points -> bit-identical output.
// LDS 64 KB -> 2 blocks/CU. launch_bounds(512,4) caps VGPR at 128.
// ---------------------------------------------------------------------------
__global__ __launch_bounds__(512, 4) void attn_fwd_mfma(
    const ushort* __restrict__ Qh, const ushort* __restrict__ Ql,
    const ushort* __restrict__ Kh, const ushort* __restrict__ Kl,
    const ushort* __restrict__ Vth, const ushort* __restrict__ Vtl,
    ushort* __restrict__ Oh, ushort* __restrict__ Ol) {
  __shared__ ushort Ks_h[64 * 64], Ks_l[64 * 64];   // K chunk [key][d]
  __shared__ ushort Vs_h[64 * 64], Vs_l[64 * 64];   // V^T chunk [d][key]
  __shared__ ushort Ps_h[128 * 64], Ps_l[128 * 64]; // P [q][key], wave-priv
  const int tid = threadIdx.x;
  const int b = blockIdx.x;
  const int h = blockIdx.y;
  const int fsel = blockIdx.z;
  const int f = (fsel < 8) ? (15 - fsel) : (fsel - 8);  // balanced pairing
  const int lane = tid & 63;
  const int wid = tid >> 6;   // 0..7
  const int l15 = lane & 15;
  const int lk = lane >> 4;
  const int qb = wid * 16;    // wave's 16 queries within the frame
  const size_t hb = ((size_t)(b * CH + h)) * CS * CHD;
  const size_t vtb = ((size_t)(b * CH + h)) * CHD * CS;

  // Q B-frags (one 16-query column per wave), pre-scaled by HD^-0.5.
  short8 qh[2], ql[2];
#pragma unroll
  for (int ks = 0; ks < 2; ++ks) {
    const size_t qoff = hb +
        (size_t)(f * CTPF + qb + l15) * CHD + ks * 32 + lk * 8;
    qh[ks] = *(const short8*)(Qh + qoff);
    ql[ks] = *(const short8*)(Ql + qoff);
  }

  f32x4 accO[4];
#pragma unroll
  for (int no = 0; no < 4; ++no) accO[no] = (f32x4){0.f, 0.f, 0.f, 0.f};
  float m = -1e30f;
  float lsum = 0.f;

  const int kf0 = (f == CNF - 1) ? 1 : 0;  // last-frame quirk
  for (int kf = kf0; kf <= f; ++kf) {
#pragma unroll 1
    for (int half = 0; half < 2; ++half) {
      const int cb = kf * CTPF + half * 64;
      __syncthreads();  // prev chunk's readers done before DMA lands
      {
        const size_t kc = hb + (size_t)cb * CHD;  // K chunk contiguous 4096
        const int u = tid * 8;                    // 512 thr x 8 = 4096
        __builtin_amdgcn_global_load_lds(
            (const __attribute__((address_space(1))) void*)(Kh + kc + u),
            (__attribute__((address_space(3))) void*)&Ks_h[u], 16, 0, 0);
        __builtin_amdgcn_global_load_lds(
            (const __attribute__((address_space(1))) void*)(Kl + kc + u),
            (__attribute__((address_space(3))) void*)&Ks_l[u], 16, 0, 0);
        const size_t va = vtb + (size_t)(u >> 6) * CS + cb + (u & 63);
        __builtin_amdgcn_global_load_lds(
            (const __attribute__((address_space(1))) void*)(Vth + va),
            (__attribute__((address_space(3))) void*)&Vs_h[u], 16, 0, 0);
        __builtin_amdgcn_global_load_lds(
            (const __attribute__((address_space(1))) void*)(Vtl + va),
            (__attribute__((address_space(3))) void*)&Vs_l[u], 16, 0, 0);
      }
      __syncthreads();  // drains vmcnt: staged data visible

      // QK^T swapped: S^T[key][q], one 16-query column
      f32x4 sacc[4];
#pragma unroll
      for (int mf = 0; mf < 4; ++mf) sacc[mf] = (f32x4){0.f, 0.f, 0.f, 0.f};
#pragma unroll
      for (int ks = 0; ks < 2; ++ks) {
        short8 kh[4], kl[4];
#pragma unroll
        for (int mf = 0; mf < 4; ++mf) {
          const int krow = mf * 16 + l15;
          const int base = krow * 64 + ((ks * 32 + lk * 8) ^ ((krow & 7) << 3));
          kh[mf] = *(const short8*)&Ks_h[base];
          kl[mf] = *(const short8*)&Ks_l[base];
        }
#pragma unroll
        for (int mf = 0; mf < 4; ++mf) {
          sacc[mf] = __builtin_amdgcn_mfma_f32_16x16x32_bf16(
              kh[mf], qh[ks], sacc[mf], 0, 0, 0);
          sacc[mf] = __builtin_amdgcn_mfma_f32_16x16x32_bf16(
              kh[mf], ql[ks], sacc[mf], 0, 0, 0);
          sacc[mf] = __builtin_amdgcn_mfma_f32_16x16x32_bf16(
              kl[mf], qh[ks], sacc[mf], 0, 0, 0);
        }
      }

      // online softmax (single query column; lane l15 = query)
      float cm = sacc[0][0];
#pragma unroll
      for (int mf = 0; mf < 4; ++mf)
#pragma unroll
        for (int i = 0; i < 4; ++i) cm = fmaxf(cm, sacc[mf][i]);
      cm = fmaxf(cm, __shfl_xor(cm, 16));
      cm = fmaxf(cm, __shfl_xor(cm, 32));
      const float mn = fmaxf(m, cm);
      const float c = __expf(m - mn);
      m = mn;
      float ps = 0.f;
      const int qrow = qb + l15;
      const int qmk = (qrow & 7) << 3;
#pragma unroll
      for (int mf = 0; mf < 4; ++mf) {
        float p0 = __expf(sacc[mf][0] - mn);
        float p1 = __expf(sacc[mf][1] - mn);
        float p2 = __expf(sacc[mf][2] - mn);
        float p3 = __expf(sacc[mf][3] - mn);
        ps += (p0 + p1) + (p2 + p3);
        const ushort h0 = f32_bf16_rne(p0), h1 = f32_bf16_rne(p1);
        const ushort h2 = f32_bf16_rne(p2), h3 = f32_bf16_rne(p3);
        uint2 hw, lw;
        hw.x = (uint32_t)h0 | ((uint32_t)h1 << 16);
        hw.y = (uint32_t)h2 | ((uint32_t)h3 << 16);
        lw.x = (uint32_t)f32_bf16_rne(p0 - bf16_f32(h0)) |
               ((uint32_t)f32_bf16_rne(p1 - bf16_f32(h1)) << 16);
        lw.y = (uint32_t)f32_bf16_rne(p2 - bf16_f32(h2)) |
               ((uint32_t)f32_bf16_rne(p3 - bf16_f32(h3)) << 16);
        const int off = qrow * 64 + ((mf * 16 + lk * 4) ^ qmk);
        *(uint2*)&Ps_h[off] = hw;
        *(uint2*)&Ps_l[off] = lw;
      }
      ps += __shfl_xor(ps, 16);
      ps += __shfl_xor(ps, 32);
      lsum = lsum * c + ps;

      // rescale O accumulator (row q = qb + lk*4 + i; c uniform across lk)
#pragma unroll
      for (int i = 0; i < 4; ++i) {
        const float cq = __shfl(c, lk * 4 + i);
#pragma unroll
        for (int no = 0; no < 4; ++no) accO[no][i] *= cq;
      }

      // PV: O[q][d] += P[q][key] * Vt[d][key]
#pragma unroll
      for (int ks = 0; ks < 2; ++ks) {
        const int prow = qb + l15;
        const int pbase = prow * 64 + ((ks * 32 + lk * 8) ^ ((prow & 7) << 3));
        const short8 pa_h = *(const short8*)&Ps_h[pbase];
        const short8 pa_l = *(const short8*)&Ps_l[pbase];
        short8 vb_h[4], vb_l[4];
#pragma unroll
        for (int no = 0; no < 4; ++no) {
          const int vrow = no * 16 + l15;
          const int base = vrow * 64 + ((ks * 32 + lk * 8) ^ ((vrow & 7) << 3));
          vb_h[no] = *(const short8*)&Vs_h[base];
          vb_l[no] = *(const short8*)&Vs_l[base];
        }
#pragma unroll
        for (int no = 0; no < 4; ++no) {
          accO[no] = __builtin_amdgcn_mfma_f32_16x16x32_bf16(
              pa_h, vb_h[no], accO[no], 0, 0, 0);
          accO[no] = __builtin_amdgcn_mfma_f32_16x16x32_bf16(
              pa_h, vb_l[no], accO[no], 0, 0, 0);
          accO[no] = __builtin_amdgcn_mfma_f32_16x16x32_bf16(
              pa_l, vb_h[no], accO[no], 0, 0, 0);
        }
      }
    }
  }

  // normalize and write O pre-split h/l in [B,S,DM] layout for GEMM2
  const float il = 1.f / lsum;
#pragma unroll
  for (int i = 0; i < 4; ++i) {
    const float wv = __shfl(il, lk * 4 + i);
    const int srow = f * CTPF + qb + lk * 4 + i;
    const size_t obase = (size_t)(b * CS + srow) * CDM + h * CHD;
#pragma unroll
    for (int no = 0; no < 4; ++no) {
      const float val = accO[no][i] * wv;
      const ushort hh = f32_bf16_rne(val);
      Oh[obase + no * 16 + l15] = hh;
      Ol[obase + no * 16 + l15] = f32_bf16_rne(val - bf16_f32(hh));
    }
  }
}

// ---------------------------------------------------------------------------
extern "C" void kernel_launch(void* const* d_in, const int* in_sizes, int n_in,
                              void* d_out, int out_size, void* d_ws, size_t ws_size,
                              hipStream_t stream) {
  const float* x       = (const float*)d_in[0];
  const float* Wqkv    = (const float*)d_in[1];
  const float* bqkv    = (const float*)d_in[2];
  const float* q_scale = (const float*)d_in[3];
  const float* k_scale = (const float*)d_in[4];
  const float* Wout    = (const float*)d_in[5];
  const float* bout    = (const float*)d_in[6];
  float* out = (float*)d_out;

  // Workspace layout (ushort units). Temporal aliasing (validated R11-R18):
  //  region0 (50.3 MB): qkv fp32 [GEMM1..prep]  ->  Oh/Ol [attn..GEMM2]
  //  region1 (50.3 MB): xh/xl/Wqh/Wql [split..GEMM1] -> Qh..Vtl [prep..attn]
  //  region2 ( 4.2 MB): Wouth/Woutl [split..GEMM2]; then 512KB trig table
  ushort* W = (ushort*)d_ws;
  const size_t qkvN = (size_t)(CB * CS) * (3 * CDM);   // 12.58M floats
  const size_t perA = (size_t)CB * CH * CS * CHD;      // 4.19M elems
  const size_t WqN  = (size_t)(3 * CDM) * CDM;         // 3.15M
  const size_t WoN  = (size_t)CDM * CDM;               // 1.05M

  float*  qkvF = (float*)W;
  ushort* Oh   = W;                    // aliases qkvF (dead after prep)
  ushort* Ol   = W + perA;
  ushort* R1   = W + 2 * qkvN;
  ushort* Qh = R1;            ushort* Ql = R1 + perA;
  ushort* Kh = R1 + 2 * perA; ushort* Kl = R1 + 3 * perA;
  ushort* Vth = R1 + 4 * perA; ushort* Vtl = R1 + 5 * perA;
  ushort* xh  = R1;            ushort* xl  = R1 + perA;   // alias Qh/Ql
  ushort* Wqh = R1 + 2 * perA; ushort* Wql = Wqh + WqN;   // alias Kh..
  ushort* Wouth = R1 + 6 * perA; ushort* Woutl = Wouth + WoN;
  float2* Trig = (float2*)(Woutl + WoN);               // 65536 float2

  // 0) one-time splits + RoPE trig table
  rope_tab<<<256, 256, 0, stream>>>(Trig);
  split3<<<2048, 256, 0, stream>>>(x, xh, xl, (int)(perA / 8),
                                   Wqkv, Wqh, Wql, (int)(WqN / 8),
                                   Wout, Wouth, Woutl, (int)(WoN / 8));

  // 1) qkv = x @ Wqkv^T + bqkv
  dim3 g1((3 * CDM) / 128, (CB * CS) / 128);
  gemm_ps<<<g1, 256, 0, stream>>>(xh, xl, Wqh, Wql, bqkv, qkvF,
                                  CB * CS, 3 * CDM, CDM);

  // 2) RMSNorm + RoPE (table); pre-split Q linear, K/V pre-swizzled
  dim3 g2(CS / 64, CH, CB);
  qkv_prep<<<g2, 256, 0, stream>>>(qkvF, q_scale, k_scale, Trig,
                                   Qh, Ql, Kh, Kl, Vth, Vtl);

  // 3) frame-block-causal attention: 512 thr = 8 waves x 16 queries
  dim3 g3(CB, CH, CNF);
  attn_fwd_mfma<<<g3, 512, 0, stream>>>(Qh, Ql, Kh, Kl, Vth, Vtl, Oh, Ol);

  // 4) out = O @ Wout^T + bout
  dim3 g4(CDM / 128, (CB * CS) / 128);
  gemm_ps<<<g4, 256, 0, stream>>>(Oh, Ol, Wouth, Woutl, bout, out,
                                  CB * CS, CDM, CDM);
}